// Round 5
// baseline (383.195 us; speedup 1.0000x reference)
//
#include <hip/hip_runtime.h>
#include <stdint.h>
#include <math.h>

typedef __bf16 bf16x8 __attribute__((ext_vector_type(8)));
typedef float f32x4 __attribute__((ext_vector_type(4)));
typedef unsigned short us8 __attribute__((ext_vector_type(8)));
typedef unsigned short us4 __attribute__((ext_vector_type(4)));

#define DD 128      // feature dim
#define TILE 64     // edges per block-tile

__device__ __forceinline__ unsigned short f2bf(float f) {
    __bf16 b = (__bf16)f;                  // native v_cvt (RNE)
    return __builtin_bit_cast(unsigned short, b);
}

__device__ __forceinline__ float fsilu(float x) {
    float e = __expf(-x);
    return x * __builtin_amdgcn_rcpf(1.0f + e);
}

__device__ __forceinline__ float dec1(unsigned int u) {
    float z = (float)(u & 0x1FFFFu) * (1.0f / 2048.0f) - 36.0f;
    float s = __builtin_amdgcn_rcpf(1.0f + __expf(-z));
    return __logf(s + 1e-10f);
}

__global__ void decode_log(unsigned int* __restrict__ p, long n) {
    long i = (long)blockIdx.x * blockDim.x + threadIdx.x;
    long stride = (long)gridDim.x * blockDim.x;
    long n4 = n >> 2;
    for (long k = i; k < n4; k += stride) {
        uint4 u = ((uint4*)p)[k];
        float4 r;
        r.x = dec1(u.x); r.y = dec1(u.y); r.z = dec1(u.z); r.w = dec1(u.w);
        ((float4*)p)[k] = r;
    }
    for (long k = (n4 << 2) + i; k < n; k += stride) {
        unsigned int u = p[k];
        ((float*)p)[k] = dec1(u);
    }
}

// Block: 256 threads = 4 waves. Tile: 64 edges x 128 features, K=128.
// L1 B-fragments are loaded DIRECTLY from global in fragment order
// (per (nt,kk): 2 dwordx4/lane cover 16 rows x 128B dense; the 4-wave
// duplication is absorbed by L1/L2). No Abuf, no stage phase.
// L2 runs through the validated Hbuf round-trip (XOR-swizzled).
// z is computed in VALU from acc2 (f32 H2 x f32 WO), reduced over
// lane-groups via shfl_xor, and across waves via a 1KB zbuf.
// 2 barriers/tile; scatter overlaps the next tile's MFMA work.
__global__ __launch_bounds__(256)
void mlp_scatter(const float* __restrict__ A,
                 const int* __restrict__ eidx,
                 const float* __restrict__ W1, const float* __restrict__ B1,
                 const float* __restrict__ W2, const float* __restrict__ B2,
                 const float* __restrict__ WO, const float* __restrict__ BO,
                 unsigned int* __restrict__ out,
                 int E, int numTiles, int tpb, int N)
{
    __shared__ unsigned short Hbuf[TILE * DD];   // 16 KB: H1 bf16 (swizzled)
    __shared__ float zbuf[TILE * 4];             // 1 KB: per-wave z partials [e][wave]

    const int tid  = threadIdx.x;
    const int lane = tid & 63;
    const int wave = tid >> 6;
    const int lrow = lane & 15;          // frag row/col index
    const int lg   = lane >> 4;          // 4 lane-groups
    const int lkb  = lg * 16;            // byte offset of this lane's 8-bf16 k-slice

    // ---- W1/W2 A-fragments: lane holds W[f = 32w+16mt+lrow][k-slice] ----
    bf16x8 w1f[2][4], w2f[2][4];
    float4 bias1[2], bias2[2], wo4[2];
    #pragma unroll
    for (int mt = 0; mt < 2; ++mt) {
        int f = wave * 32 + mt * 16 + lrow;
        bias1[mt] = *(const float4*)(B1 + wave * 32 + mt * 16 + lg * 4);
        bias2[mt] = *(const float4*)(B2 + wave * 32 + mt * 16 + lg * 4);
        wo4[mt]   = *(const float4*)(WO + wave * 32 + mt * 16 + lg * 4);
        #pragma unroll
        for (int kk = 0; kk < 4; ++kk) {
            const float* p1 = W1 + f * DD + kk * 32 + lg * 8;
            const float* p2 = W2 + f * DD + kk * 32 + lg * 8;
            us8 t1, t2;
            #pragma unroll
            for (int j = 0; j < 8; ++j) { t1[j] = f2bf(p1[j]); t2[j] = f2bf(p2[j]); }
            w1f[mt][kk] = __builtin_bit_cast(bf16x8, t1);
            w2f[mt][kk] = __builtin_bit_cast(bf16x8, t2);
        }
    }
    const float bo = BO[0];
    const size_t NN = (size_t)N * (size_t)N;

    for (int t = blockIdx.x; t < numTiles; t += (int)gridDim.x) {
        // ---- hoist eidx loads for this tile's scatter ----
        int i0 = 0, j0 = 0, sb = 0, sei = 0;
        if (lane < 16) {
            int e = wave * 16 + lane;
            sb  = t / tpb;
            sei = (t - sb * tpb) * TILE + e;
            i0 = eidx[(size_t)(2 * sb) * E + sei];
            j0 = eidx[(size_t)(2 * sb + 1) * E + sei];
        }

        const float* At = A + (long)t * TILE * DD;

        // ---- layer 1 (swapped): B-frags direct from global ----
        f32x4 acc1[2][4];
        #pragma unroll
        for (int mt = 0; mt < 2; ++mt)
            #pragma unroll
            for (int nt = 0; nt < 4; ++nt)
                acc1[mt][nt] = (f32x4){0.f, 0.f, 0.f, 0.f};
        #pragma unroll
        for (int kk = 0; kk < 4; ++kk) {
            bf16x8 ef[4];
            #pragma unroll
            for (int nt = 0; nt < 4; ++nt) {
                const float* p = At + (nt * 16 + lrow) * DD + kk * 32 + lg * 8;
                float4 a0 = *(const float4*)p;
                float4 a1 = *(const float4*)(p + 4);
                us8 tt;
                tt[0] = f2bf(a0.x); tt[1] = f2bf(a0.y); tt[2] = f2bf(a0.z); tt[3] = f2bf(a0.w);
                tt[4] = f2bf(a1.x); tt[5] = f2bf(a1.y); tt[6] = f2bf(a1.z); tt[7] = f2bf(a1.w);
                ef[nt] = __builtin_bit_cast(bf16x8, tt);
            }
            #pragma unroll
            for (int mt = 0; mt < 2; ++mt)
                #pragma unroll
                for (int nt = 0; nt < 4; ++nt)
                    acc1[mt][nt] = __builtin_amdgcn_mfma_f32_16x16x32_bf16(w1f[mt][kk], ef[nt], acc1[mt][nt], 0, 0, 0);
        }
        // epilogue: silu+bias, packed b64 writes into Hbuf[e][f] (swizzled).
        // Safe without a barrier: all waves' L2 reads of the previous tile's
        // Hbuf completed before the previous B2.
        #pragma unroll
        for (int mt = 0; mt < 2; ++mt)
            #pragma unroll
            for (int nt = 0; nt < 4; ++nt) {
                int e  = nt * 16 + lrow;
                int fb = (wave * 32 + mt * 16 + lg * 4) * 2;   // byte col of f0
                us4 o;
                #pragma unroll
                for (int i = 0; i < 4; ++i) {
                    float h = fsilu(acc1[mt][nt][i] + bias1[mt][i]);
                    o[i] = f2bf(h);
                }
                *(us4*)((char*)Hbuf + e * 256 + (fb ^ ((e & 7) << 4))) = o;
            }
        __syncthreads();   // B1: H1 visible to all waves

        // ---- layer 2 (swapped): reads H1 from Hbuf ----
        f32x4 acc2[2][4];
        #pragma unroll
        for (int mt = 0; mt < 2; ++mt)
            #pragma unroll
            for (int nt = 0; nt < 4; ++nt)
                acc2[mt][nt] = (f32x4){0.f, 0.f, 0.f, 0.f};
        #pragma unroll
        for (int kk = 0; kk < 4; ++kk) {
            bf16x8 ef[4];
            #pragma unroll
            for (int nt = 0; nt < 4; ++nt) {
                int e = nt * 16 + lrow;
                ef[nt] = *(const bf16x8*)((const char*)Hbuf + e * 256 +
                                          ((kk * 64 + lkb) ^ ((e & 7) << 4)));
            }
            #pragma unroll
            for (int mt = 0; mt < 2; ++mt)
                #pragma unroll
                for (int nt = 0; nt < 4; ++nt)
                    acc2[mt][nt] = __builtin_amdgcn_mfma_f32_16x16x32_bf16(w2f[mt][kk], ef[nt], acc2[mt][nt], 0, 0, 0);
        }

        // ---- z partials in VALU: zp[nt] = sum over this wave's f-slice ----
        float zp[4] = {0.f, 0.f, 0.f, 0.f};
        #pragma unroll
        for (int mt = 0; mt < 2; ++mt)
            #pragma unroll
            for (int nt = 0; nt < 4; ++nt)
                #pragma unroll
                for (int i = 0; i < 4; ++i) {
                    float h = fsilu(acc2[mt][nt][i] + bias2[mt][i]);
                    zp[nt] += wo4[mt][i] * h;
                }
        // reduce over the 4 lane-groups (lane bits 4-5)
        #pragma unroll
        for (int nt = 0; nt < 4; ++nt) {
            zp[nt] += __shfl_xor(zp[nt], 16);
            zp[nt] += __shfl_xor(zp[nt], 32);
        }
        if (lg == 0) {
            #pragma unroll
            for (int nt = 0; nt < 4; ++nt)
                zbuf[(nt * 16 + lrow) * 4 + wave] = zp[nt];
        }
        __syncthreads();   // B2: z partials visible; Hbuf free for next tile

        // ---- final z, pack, atomicMax scatter (16 lanes/wave, 64 edges) ----
        if (lane < 16) {
            int e = wave * 16 + lane;
            float4 zb = *(const float4*)&zbuf[e * 4];
            float z = ((zb.x + zb.y) + (zb.z + zb.w)) + bo;
            int qz = (int)((z + 36.0f) * 2048.0f + 0.5f);
            qz = qz < 0 ? 0 : (qz > 131071 ? 131071 : qz);
            unsigned int packed = (((unsigned int)(sei + 1)) << 17) | (unsigned int)qz;
            atomicMax(&out[(size_t)sb * NN + (size_t)i0 * N + (size_t)j0], packed);
        }
    }
}

extern "C" void kernel_launch(void* const* d_in, const int* in_sizes, int n_in,
                              void* d_out, int out_size, void* d_ws, size_t ws_size,
                              hipStream_t stream) {
    const float* edge_attr  = (const float*)d_in[0];
    const int*   edge_index = (const int*)d_in[1];
    const float* W1   = (const float*)d_in[2];
    const float* b1   = (const float*)d_in[3];
    const float* W2   = (const float*)d_in[4];
    const float* b2   = (const float*)d_in[5];
    const float* Wout = (const float*)d_in[6];
    const float* bout = (const float*)d_in[7];

    long rows = (long)in_sizes[0] / DD;        // B*E = 1,024,000
    int  E    = in_sizes[1] / 64;              // 32000 (B=32)
    int  numTiles = (int)(rows / TILE);        // 16000
    int  tpb  = E / TILE;                      // tiles per batch = 500
    int  Bb   = (int)(rows / E);               // 32
    int  N    = (int)(sqrtf((float)(out_size / Bb)) + 0.5f);   // 1000

    unsigned int* outp = (unsigned int*)d_out;
    long n = (long)out_size;

    hipMemsetAsync(d_out, 0, (size_t)out_size * sizeof(unsigned int), stream);
    mlp_scatter<<<2048, 256, 0, stream>>>(edge_attr, edge_index, W1, b1, W2, b2,
                                          Wout, bout, outp, E, numTiles, tpb, N);
    decode_log<<<2048, 256, 0, stream>>>(outp, n);
}

// Round 6
// 237.161 us; speedup vs baseline: 1.6158x; 1.6158x over previous
//
#include <hip/hip_runtime.h>
#include <stdint.h>
#include <math.h>

typedef __bf16 bf16x8 __attribute__((ext_vector_type(8)));
typedef float f32x4 __attribute__((ext_vector_type(4)));
typedef unsigned short us8 __attribute__((ext_vector_type(8)));
typedef unsigned short us4 __attribute__((ext_vector_type(4)));

#define DD 128      // feature dim
#define TILE 64     // edges per block-tile

__device__ __forceinline__ unsigned short f2bf(float f) {
    __bf16 b = (__bf16)f;                  // native v_cvt (RNE)
    return __builtin_bit_cast(unsigned short, b);
}

__device__ __forceinline__ float fsilu(float x) {
    float e = __expf(-x);
    return x * __builtin_amdgcn_rcpf(1.0f + e);
}

__device__ __forceinline__ float dec1(unsigned int u) {
    float z = (float)(u & 0x1FFFFu) * (1.0f / 2048.0f) - 36.0f;
    float s = __builtin_amdgcn_rcpf(1.0f + __expf(-z));
    return __logf(s + 1e-10f);
}

__global__ void decode_log(unsigned int* __restrict__ p, long n) {
    long i = (long)blockIdx.x * blockDim.x + threadIdx.x;
    long stride = (long)gridDim.x * blockDim.x;
    long n4 = n >> 2;
    for (long k = i; k < n4; k += stride) {
        uint4 u = ((uint4*)p)[k];
        float4 r;
        r.x = dec1(u.x); r.y = dec1(u.y); r.z = dec1(u.z); r.w = dec1(u.w);
        ((float4*)p)[k] = r;
    }
    for (long k = (n4 << 2) + i; k < n; k += stride) {
        unsigned int u = p[k];
        ((float*)p)[k] = dec1(u);
    }
}

// Block: 256 threads = 4 waves. Tile: 64 edges x 128 features, K=128.
// Round-4 validated core (coalesced float4 stage -> XOR-swizzled LDS ->
// swapped-operand MFMA, packed b64 epilogues) restructured to 2 barriers/tile:
//   L1(read Abuf[t], MFMA, silu -> Hbuf)
//   S1  (Hbuf ready; Abuf reads done)
//   stage Abuf <- v (tile t+1)  |  prefetch v <- tile t+2  |  L2(read Hbuf,
//   MFMA) ; z = WO.silu(acc2+b2) in VALU, shfl_xor over lane-groups -> zbuf
//   S2  (zbuf ready; Hbuf reads done; Abuf staged)
//   scatter (16 lanes/wave, atomicMax packed (ei+1)<<17|qz)
// H2 never touches LDS; no z-MFMA phase.
__global__ __launch_bounds__(256)
void mlp_scatter(const float* __restrict__ A,
                 const int* __restrict__ eidx,
                 const float* __restrict__ W1, const float* __restrict__ B1,
                 const float* __restrict__ W2, const float* __restrict__ B2,
                 const float* __restrict__ WO, const float* __restrict__ BO,
                 unsigned int* __restrict__ out,
                 int E, int numTiles, int tpb, int N)
{
    __shared__ unsigned short Abuf[TILE * DD];   // 16 KB: edge_attr bf16 (swizzled)
    __shared__ unsigned short Hbuf[TILE * DD];   // 16 KB: H1 bf16 (swizzled)
    __shared__ float zbuf[TILE * 4];             // 1 KB: per-wave z partials [e][wave]

    const int tid  = threadIdx.x;
    const int lane = tid & 63;
    const int wave = tid >> 6;
    const int lrow = lane & 15;          // frag row/col index
    const int lg   = lane >> 4;          // 4 lane-groups
    const int lkb  = lg * 16;            // byte offset of this lane's 8-bf16 k-slice

    // ---- W1/W2 A-fragments: lane holds W[f = 32w+16mt+lrow][k-slice] ----
    bf16x8 w1f[2][4], w2f[2][4];
    float4 bias1[2], bias2[2], wo4[2];
    #pragma unroll
    for (int mt = 0; mt < 2; ++mt) {
        int f = wave * 32 + mt * 16 + lrow;
        bias1[mt] = *(const float4*)(B1 + wave * 32 + mt * 16 + lg * 4);
        bias2[mt] = *(const float4*)(B2 + wave * 32 + mt * 16 + lg * 4);
        wo4[mt]   = *(const float4*)(WO + wave * 32 + mt * 16 + lg * 4);
        #pragma unroll
        for (int kk = 0; kk < 4; ++kk) {
            const float* p1 = W1 + f * DD + kk * 32 + lg * 8;
            const float* p2 = W2 + f * DD + kk * 32 + lg * 8;
            us8 t1, t2;
            #pragma unroll
            for (int j = 0; j < 8; ++j) { t1[j] = f2bf(p1[j]); t2[j] = f2bf(p2[j]); }
            w1f[mt][kk] = __builtin_bit_cast(bf16x8, t1);
            w2f[mt][kk] = __builtin_bit_cast(bf16x8, t2);
        }
    }
    const float bo = BO[0];
    const size_t NN = (size_t)N * (size_t)N;
    const int gs = (int)gridDim.x;

    int t0 = blockIdx.x;
    if (t0 >= numTiles) return;

    // ---- prologue: load + stage tile t0, prefetch t0+gs ----
    float4 v[8];
    {
        const float4* src = (const float4*)(A + (long)t0 * TILE * DD);
        #pragma unroll
        for (int s = 0; s < 8; ++s) v[s] = src[s * 256 + tid];
    }
    #pragma unroll
    for (int s = 0; s < 8; ++s) {
        int id  = s * 256 + tid;           // 2048 float4 = 64 rows x 32
        int row = id >> 5;
        int cb  = (id & 31) * 8;           // byte offset (4 ushorts)
        us4 o;
        o[0] = f2bf(v[s].x); o[1] = f2bf(v[s].y); o[2] = f2bf(v[s].z); o[3] = f2bf(v[s].w);
        *(us4*)((char*)Abuf + row * 256 + (cb ^ ((row & 7) << 4))) = o;
    }
    {
        int tn = t0 + gs; if (tn >= numTiles) tn = t0;
        const float4* src = (const float4*)(A + (long)tn * TILE * DD);
        #pragma unroll
        for (int s = 0; s < 8; ++s) v[s] = src[s * 256 + tid];
    }
    __syncthreads();

    for (int t = t0; t < numTiles; t += gs) {
        // ---- hoist eidx loads for this tile's scatter ----
        int i0 = 0, j0 = 0, sb = 0, sei = 0;
        if (lane < 16) {
            int e = wave * 16 + lane;
            sb  = t / tpb;
            sei = (t - sb * tpb) * TILE + e;
            i0 = eidx[(size_t)(2 * sb) * E + sei];
            j0 = eidx[(size_t)(2 * sb + 1) * E + sei];
        }

        // ---- layer 1 (swapped): C1[f][e] from Abuf ----
        f32x4 acc1[2][4];
        #pragma unroll
        for (int mt = 0; mt < 2; ++mt)
            #pragma unroll
            for (int nt = 0; nt < 4; ++nt)
                acc1[mt][nt] = (f32x4){0.f, 0.f, 0.f, 0.f};
        #pragma unroll
        for (int kk = 0; kk < 4; ++kk) {
            bf16x8 ef[4];
            #pragma unroll
            for (int nt = 0; nt < 4; ++nt) {
                int e = nt * 16 + lrow;
                ef[nt] = *(const bf16x8*)((const char*)Abuf + e * 256 +
                                          ((kk * 64 + lkb) ^ ((e & 7) << 4)));
            }
            #pragma unroll
            for (int mt = 0; mt < 2; ++mt)
                #pragma unroll
                for (int nt = 0; nt < 4; ++nt)
                    acc1[mt][nt] = __builtin_amdgcn_mfma_f32_16x16x32_bf16(w1f[mt][kk], ef[nt], acc1[mt][nt], 0, 0, 0);
        }
        // epilogue: silu+bias -> packed b64 writes into Hbuf[e][f] (swizzled)
        #pragma unroll
        for (int mt = 0; mt < 2; ++mt)
            #pragma unroll
            for (int nt = 0; nt < 4; ++nt) {
                int e  = nt * 16 + lrow;
                int fb = (wave * 32 + mt * 16 + lg * 4) * 2;   // byte col of f0
                us4 o;
                #pragma unroll
                for (int i = 0; i < 4; ++i) {
                    float h = fsilu(acc1[mt][nt][i] + bias1[mt][i]);
                    o[i] = f2bf(h);
                }
                *(us4*)((char*)Hbuf + e * 256 + (fb ^ ((e & 7) << 4))) = o;
            }
        __syncthreads();   // S1: Hbuf ready; all Abuf reads of tile t done

        // ---- stage tile t+gs from v into Abuf (overlaps L2 below) ----
        #pragma unroll
        for (int s = 0; s < 8; ++s) {
            int id  = s * 256 + tid;
            int row = id >> 5;
            int cb  = (id & 31) * 8;
            us4 o;
            o[0] = f2bf(v[s].x); o[1] = f2bf(v[s].y); o[2] = f2bf(v[s].z); o[3] = f2bf(v[s].w);
            *(us4*)((char*)Abuf + row * 256 + (cb ^ ((row & 7) << 4))) = o;
        }
        // ---- prefetch tile t+2*gs into v ----
        {
            int tn = t + 2 * gs; if (tn >= numTiles) tn = t;
            const float4* src = (const float4*)(A + (long)tn * TILE * DD);
            #pragma unroll
            for (int s = 0; s < 8; ++s) v[s] = src[s * 256 + tid];
        }

        // ---- layer 2 (swapped): C2[f][e] from Hbuf; H2 stays in regs ----
        f32x4 acc2[2][4];
        #pragma unroll
        for (int mt = 0; mt < 2; ++mt)
            #pragma unroll
            for (int nt = 0; nt < 4; ++nt)
                acc2[mt][nt] = (f32x4){0.f, 0.f, 0.f, 0.f};
        #pragma unroll
        for (int kk = 0; kk < 4; ++kk) {
            bf16x8 ef[4];
            #pragma unroll
            for (int nt = 0; nt < 4; ++nt) {
                int e = nt * 16 + lrow;
                ef[nt] = *(const bf16x8*)((const char*)Hbuf + e * 256 +
                                          ((kk * 64 + lkb) ^ ((e & 7) << 4)));
            }
            #pragma unroll
            for (int mt = 0; mt < 2; ++mt)
                #pragma unroll
                for (int nt = 0; nt < 4; ++nt)
                    acc2[mt][nt] = __builtin_amdgcn_mfma_f32_16x16x32_bf16(w2f[mt][kk], ef[nt], acc2[mt][nt], 0, 0, 0);
        }

        // ---- z partials in VALU: zp[nt] = sum over this wave's f-slice ----
        float zp[4] = {0.f, 0.f, 0.f, 0.f};
        #pragma unroll
        for (int mt = 0; mt < 2; ++mt)
            #pragma unroll
            for (int nt = 0; nt < 4; ++nt)
                #pragma unroll
                for (int i = 0; i < 4; ++i) {
                    float h = fsilu(acc2[mt][nt][i] + bias2[mt][i]);
                    zp[nt] += wo4[mt][i] * h;
                }
        #pragma unroll
        for (int nt = 0; nt < 4; ++nt) {        // reduce over lane-groups
            zp[nt] += __shfl_xor(zp[nt], 16);
            zp[nt] += __shfl_xor(zp[nt], 32);
        }
        if (lg == 0) {
            #pragma unroll
            for (int nt = 0; nt < 4; ++nt)
                zbuf[(nt * 16 + lrow) * 4 + wave] = zp[nt];
        }
        __syncthreads();   // S2: zbuf ready; Hbuf reads done; Abuf staged

        // ---- final z, pack, atomicMax scatter (16 lanes/wave, 64 edges) ----
        if (lane < 16) {
            int e = wave * 16 + lane;
            float4 zb = *(const float4*)&zbuf[e * 4];
            float z = ((zb.x + zb.y) + (zb.z + zb.w)) + bo;
            int qz = (int)((z + 36.0f) * 2048.0f + 0.5f);
            qz = qz < 0 ? 0 : (qz > 131071 ? 131071 : qz);
            unsigned int packed = (((unsigned int)(sei + 1)) << 17) | (unsigned int)qz;
            atomicMax(&out[(size_t)sb * NN + (size_t)i0 * N + (size_t)j0], packed);
        }
    }
}

extern "C" void kernel_launch(void* const* d_in, const int* in_sizes, int n_in,
                              void* d_out, int out_size, void* d_ws, size_t ws_size,
                              hipStream_t stream) {
    const float* edge_attr  = (const float*)d_in[0];
    const int*   edge_index = (const int*)d_in[1];
    const float* W1   = (const float*)d_in[2];
    const float* b1   = (const float*)d_in[3];
    const float* W2   = (const float*)d_in[4];
    const float* b2   = (const float*)d_in[5];
    const float* Wout = (const float*)d_in[6];
    const float* bout = (const float*)d_in[7];

    long rows = (long)in_sizes[0] / DD;        // B*E = 1,024,000
    int  E    = in_sizes[1] / 64;              // 32000 (B=32)
    int  numTiles = (int)(rows / TILE);        // 16000
    int  tpb  = E / TILE;                      // tiles per batch = 500
    int  Bb   = (int)(rows / E);               // 32
    int  N    = (int)(sqrtf((float)(out_size / Bb)) + 0.5f);   // 1000

    unsigned int* outp = (unsigned int*)d_out;
    long n = (long)out_size;

    hipMemsetAsync(d_out, 0, (size_t)out_size * sizeof(unsigned int), stream);
    mlp_scatter<<<2048, 256, 0, stream>>>(edge_attr, edge_index, W1, b1, W2, b2,
                                          Wout, bout, outp, E, numTiles, tpb, N);
    decode_log<<<2048, 256, 0, stream>>>(outp, n);
}